// Round 1
// baseline (7181.594 us; speedup 1.0000x reference)
//
#include <hip/hip_runtime.h>
#include <cstdint>
#include <cstddef>

// Problem constants (match reference)
#define DIMS   1024
#define VOCAB  32000
#define BATCH  16
#define TSTEPS 128
#define GDIM   (4 * DIMS)   // 4096 gate columns

__device__ __forceinline__ float sigmoidf_(float x) {
    return 1.0f / (1.0f + __expf(-x));
}

// ---------------------------------------------------------------------------
// Zero-init h0 (slot 0 of h_all) and c0. ws is poisoned 0xAA before each call.
// ---------------------------------------------------------------------------
__global__ void zero_hc(float* __restrict__ h0, float* __restrict__ c0) {
    int i = blockIdx.x * blockDim.x + threadIdx.x;
    if (i < BATCH * DIMS) { h0[i] = 0.f; c0[i] = 0.f; }
}

// ---------------------------------------------------------------------------
// f32 GEMM: C[M,N] = A[M,K] @ B[N,K]^T + bias[N]
// Tile 128x128, K-tile 16, 256 threads, 8x8 accumulators/thread.
// USE_IDX=1: A row r comes from emb[idx[(r&15)*TSTEPS + (r>>4)]] (r = t*16+b).
// M is implied by gridDim.y*128 (always 2048 here; all dims divide exactly).
// ---------------------------------------------------------------------------
template <int USE_IDX>
__global__ __launch_bounds__(256)
void gemm_bt_bias(const float* __restrict__ A,
                  const float* __restrict__ B,
                  const float* __restrict__ bias,
                  float* __restrict__ C,
                  const int* __restrict__ idx,
                  int N, int K)
{
    __shared__ float As[16][128];   // [k][m]
    __shared__ float Bs[16][128];   // [k][n]

    const int tid = threadIdx.x;
    const int m0  = blockIdx.y * 128;
    const int n0  = blockIdx.x * 128;

    // Loader mapping: each thread loads 8 contiguous k of one row (2 float4).
    const int lm = tid >> 1;          // 0..127 tile row
    const int lk = (tid & 1) * 8;     // 0 or 8

    const float* Arow;
    {
        int arow = m0 + lm;
        long aoff;
        if (USE_IDX) {
            int t_ = arow >> 4;       // r = t*16 + b
            int b_ = arow & 15;
            aoff = (long)idx[b_ * TSTEPS + t_] * K;   // emb gather fused here
        } else {
            aoff = (long)arow * K;
        }
        Arow = A + aoff;
    }
    const float* Brow = B + (long)(n0 + lm) * K;

    // Compute mapping: 8x8 per thread
    const int tm = (tid & 15) * 8;
    const int tn = (tid >> 4) * 8;

    float acc[8][8];
    #pragma unroll
    for (int i = 0; i < 8; ++i)
        #pragma unroll
        for (int j = 0; j < 8; ++j) acc[i][j] = 0.f;

    for (int k0 = 0; k0 < K; k0 += 16) {
        // Issue global loads before the barrier (hide latency under prev compute)
        float4 a0 = *(const float4*)(Arow + k0 + lk);
        float4 a1 = *(const float4*)(Arow + k0 + lk + 4);
        float4 b0 = *(const float4*)(Brow + k0 + lk);
        float4 b1 = *(const float4*)(Brow + k0 + lk + 4);

        __syncthreads();  // previous tile's compute done before overwrite
        As[lk + 0][lm] = a0.x; As[lk + 1][lm] = a0.y;
        As[lk + 2][lm] = a0.z; As[lk + 3][lm] = a0.w;
        As[lk + 4][lm] = a1.x; As[lk + 5][lm] = a1.y;
        As[lk + 6][lm] = a1.z; As[lk + 7][lm] = a1.w;
        Bs[lk + 0][lm] = b0.x; Bs[lk + 1][lm] = b0.y;
        Bs[lk + 2][lm] = b0.z; Bs[lk + 3][lm] = b0.w;
        Bs[lk + 4][lm] = b1.x; Bs[lk + 5][lm] = b1.y;
        Bs[lk + 6][lm] = b1.z; Bs[lk + 7][lm] = b1.w;
        __syncthreads();

        #pragma unroll
        for (int k = 0; k < 16; ++k) {
            float4 av0 = *(const float4*)&As[k][tm];
            float4 av1 = *(const float4*)&As[k][tm + 4];
            float4 bv0 = *(const float4*)&Bs[k][tn];
            float4 bv1 = *(const float4*)&Bs[k][tn + 4];
            float am[8] = {av0.x, av0.y, av0.z, av0.w, av1.x, av1.y, av1.z, av1.w};
            float bn[8] = {bv0.x, bv0.y, bv0.z, bv0.w, bv1.x, bv1.y, bv1.z, bv1.w};
            #pragma unroll
            for (int i = 0; i < 8; ++i)
                #pragma unroll
                for (int j = 0; j < 8; ++j)
                    acc[i][j] += am[i] * bn[j];
        }
    }

    // Epilogue: + bias, coalesced float4 stores
    float bv[8];
    #pragma unroll
    for (int j = 0; j < 8; ++j) bv[j] = bias[n0 + tn + j];
    #pragma unroll
    for (int i = 0; i < 8; ++i) {
        float* crow = C + (size_t)(m0 + tm + i) * N + (n0 + tn);
        float4 o0 = make_float4(acc[i][0] + bv[0], acc[i][1] + bv[1],
                                acc[i][2] + bv[2], acc[i][3] + bv[3]);
        float4 o1 = make_float4(acc[i][4] + bv[4], acc[i][5] + bv[5],
                                acc[i][6] + bv[6], acc[i][7] + bv[7]);
        *(float4*)(crow)     = o0;
        *(float4*)(crow + 4) = o1;
    }
}

// ---------------------------------------------------------------------------
// One LSTM timestep, fused: gates = gx_t + h_prev @ Wh^T; cell update.
// Grid 256 blocks x 256 threads. Block owns d-slice of 4 (d0 = blockIdx*4)
// across ALL FOUR gate chunks, so the cell update is block-local via LDS.
// Thread (b = tid&15, row = tid>>4): row = gate*4 + dl -> j = gate*1024+d0+dl.
// h read from global (64 KB, L2/L3-hot); Wh rows from L2 (16 MB, resident).
// ---------------------------------------------------------------------------
__global__ __launch_bounds__(256)
void lstm_step(const float* __restrict__ gx_t,    // [16][4096] precomputed x-gates
               const float* __restrict__ Wh,      // [4096][1024]
               const float* __restrict__ h_prev,  // [16][1024]
               float* __restrict__ h_out,         // [16][1024]
               float* __restrict__ cbuf)          // [16][1024] in/out
{
    __shared__ float g_lds[16][17];   // [row][b], padded

    const int tid = threadIdx.x;
    const int b   = tid & 15;
    const int row = tid >> 4;         // 0..15
    const int g   = row >> 2;         // gate 0..3 (i,f,o,g)
    const int dl  = row & 3;
    const int d0  = blockIdx.x * 4;
    const int j   = g * 1024 + d0 + dl;

    const float* w = Wh + (long)j * DIMS;
    const float* h = h_prev + b * DIMS;

    // 4 independent FMA chains (acc components) to avoid latency stalls
    float4 acc = make_float4(0.f, 0.f, 0.f, 0.f);
    #pragma unroll 8
    for (int k = 0; k < DIMS; k += 4) {
        float4 wv = *(const float4*)(w + k);
        float4 hv = *(const float4*)(h + k);
        acc.x += wv.x * hv.x;
        acc.y += wv.y * hv.y;
        acc.z += wv.z * hv.z;
        acc.w += wv.w * hv.w;
    }
    float gate = acc.x + acc.y + acc.z + acc.w + gx_t[b * GDIM + j];
    g_lds[row][b] = gate;
    __syncthreads();

    if (tid < 64) {   // 16 b x 4 dl cell updates
        int bb = tid & 15;
        int dd = tid >> 4;            // 0..3
        float iv = sigmoidf_(g_lds[0 * 4 + dd][bb]);
        float fv = sigmoidf_(g_lds[1 * 4 + dd][bb]);
        float ov = sigmoidf_(g_lds[2 * 4 + dd][bb]);
        float gv = tanhf    (g_lds[3 * 4 + dd][bb]);
        int d = d0 + dd;
        float c_old = cbuf[bb * DIMS + d];
        float c_new = fv * c_old + iv * gv;
        cbuf[bb * DIMS + d]  = c_new;
        h_out[bb * DIMS + d] = ov * tanhf(c_new);
    }
}

// ---------------------------------------------------------------------------
// In-place log-softmax over each row of out[2048][32000].
// One block per row; 3 passes (max, sum-exp, normalize); passes 2-3 L2-hot.
// ---------------------------------------------------------------------------
__device__ __forceinline__ float wave_max_(float v) {
    #pragma unroll
    for (int off = 32; off > 0; off >>= 1)
        v = fmaxf(v, __shfl_xor(v, off));
    return v;
}
__device__ __forceinline__ float wave_sum_(float v) {
    #pragma unroll
    for (int off = 32; off > 0; off >>= 1)
        v += __shfl_xor(v, off);
    return v;
}

__global__ __launch_bounds__(256)
void logsoftmax_rows(float* __restrict__ out)
{
    float* rowp = out + (size_t)blockIdx.x * VOCAB;
    const int tid = threadIdx.x;
    __shared__ float redm[4], reds[4];

    // pass 1: max
    float m = -INFINITY;
    for (int i = tid * 4; i < VOCAB; i += 1024) {
        float4 v = *(const float4*)(rowp + i);
        m = fmaxf(m, fmaxf(fmaxf(v.x, v.y), fmaxf(v.z, v.w)));
    }
    m = wave_max_(m);
    if ((tid & 63) == 0) redm[tid >> 6] = m;
    __syncthreads();
    m = fmaxf(fmaxf(redm[0], redm[1]), fmaxf(redm[2], redm[3]));

    // pass 2: sum exp(v - m)
    float s = 0.f;
    for (int i = tid * 4; i < VOCAB; i += 1024) {
        float4 v = *(const float4*)(rowp + i);
        s += __expf(v.x - m) + __expf(v.y - m) + __expf(v.z - m) + __expf(v.w - m);
    }
    s = wave_sum_(s);
    if ((tid & 63) == 0) reds[tid >> 6] = s;
    __syncthreads();
    s = reds[0] + reds[1] + reds[2] + reds[3];
    const float lse = m + __logf(s);

    // pass 3: normalize
    for (int i = tid * 4; i < VOCAB; i += 1024) {
        float4 v = *(const float4*)(rowp + i);
        v.x -= lse; v.y -= lse; v.z -= lse; v.w -= lse;
        *(float4*)(rowp + i) = v;
    }
}

// ---------------------------------------------------------------------------
// Orchestration.
//   ws layout: gx   [2048][4096] f32   (33.55 MB)
//              h_all[2064][1024] f32   ( 8.45 MB)  slot s holds h_{s-1}; slot0=0
//              cbuf [  16][1024] f32   ( 64 KB)
// Inputs: idx, emb, Wx_w, Wx_b, Wh_w, fc_w, fc_b
// ---------------------------------------------------------------------------
extern "C" void kernel_launch(void* const* d_in, const int* in_sizes, int n_in,
                              void* d_out, int out_size, void* d_ws, size_t ws_size,
                              hipStream_t stream)
{
    const int*   idx  = (const int*)  d_in[0];
    const float* emb  = (const float*)d_in[1];
    const float* Wx_w = (const float*)d_in[2];
    const float* Wx_b = (const float*)d_in[3];
    const float* Wh_w = (const float*)d_in[4];
    const float* fc_w = (const float*)d_in[5];
    const float* fc_b = (const float*)d_in[6];
    float* out = (float*)d_out;

    float* gx    = (float*)d_ws;                         // [2048][4096]
    float* h_all = gx + (size_t)2048 * GDIM;             // [2064][1024]
    float* cbuf  = h_all + (size_t)(TSTEPS + 1) * BATCH * DIMS;  // [16][1024]

    const int R = TSTEPS * BATCH;  // 2048 rows

    // h0 = c0 = 0
    zero_hc<<<(BATCH * DIMS + 255) / 256, 256, 0, stream>>>(h_all, cbuf);

    // GEMM1: gx[r][j] = emb[idx(r)] . Wx_w[j] + Wx_b[j]   (gather fused)
    {
        dim3 grid(GDIM / 128, R / 128);   // (32, 16)
        gemm_bt_bias<1><<<grid, 256, 0, stream>>>(emb, Wx_w, Wx_b, gx, idx,
                                                  GDIM, DIMS);
    }

    // Recurrence: 128 fused step kernels
    for (int t = 0; t < TSTEPS; ++t) {
        lstm_step<<<DIMS / 4, 256, 0, stream>>>(
            gx + (size_t)t * BATCH * GDIM,
            Wh_w,
            h_all + (size_t)t       * BATCH * DIMS,
            h_all + (size_t)(t + 1) * BATCH * DIMS,
            cbuf);
    }

    // GEMM2: logits[r][v] = h_t(r) . fc_w[v] + fc_b[v]  -> straight into d_out
    {
        dim3 grid(VOCAB / 128, R / 128);  // (250, 16)
        gemm_bt_bias<0><<<grid, 256, 0, stream>>>(h_all + (size_t)BATCH * DIMS,
                                                  fc_w, fc_b, out, nullptr,
                                                  VOCAB, DIMS);
    }

    // log_softmax in-place over each of the 2048 rows
    logsoftmax_rows<<<R, 256, 0, stream>>>(out);
}

// Round 2
// 3076.315 us; speedup vs baseline: 2.3345x; 2.3345x over previous
//
#include <hip/hip_runtime.h>
#include <cstdint>
#include <cstddef>

#define DIMS   1024
#define VOCAB  32000
#define BATCH  16
#define TSTEPS 128
#define GDIM   (4 * DIMS)

typedef __attribute__((ext_vector_type(8))) short  short8;   // 8 bf16 (4 VGPR)
typedef __attribute__((ext_vector_type(4))) float  f32x4;    // MFMA acc

typedef unsigned short ushort_t;

__device__ __forceinline__ unsigned short f2bf(float f) {
    union { float f; unsigned u; } v; v.f = f;
    unsigned r = v.u + 0x7fffu + ((v.u >> 16) & 1u);   // RNE
    return (unsigned short)(r >> 16);
}
__device__ __forceinline__ float bf2f(unsigned short h) {
    union { unsigned u; float f; } v; v.u = ((unsigned)h) << 16;
    return v.f;
}
__device__ __forceinline__ float sigmoidf_(float x) {
    return 1.0f / (1.0f + __expf(-x));
}

__device__ __forceinline__ void gload_lds16(const void* g, void* lds) {
    __builtin_amdgcn_global_load_lds(
        (const __attribute__((address_space(1))) void*)g,
        (__attribute__((address_space(3))) void*)lds, 16, 0, 0);
}

// ---------------------------------------------------------------------------
// f32 -> bf16 conversions (one-time per call; ws re-poisoned each launch)
// ---------------------------------------------------------------------------
__global__ __launch_bounds__(256) void cvt_bf16(const float* __restrict__ in,
                                                ushort_t* __restrict__ out, long n8) {
    long c = (long)blockIdx.x * blockDim.x + threadIdx.x;
    if (c >= n8) return;
    const float* s = in + c * 8;
    float4 f0 = *(const float4*)(s);
    float4 f1 = *(const float4*)(s + 4);
    ushort_t o[8] = {f2bf(f0.x), f2bf(f0.y), f2bf(f0.z), f2bf(f0.w),
                     f2bf(f1.x), f2bf(f1.y), f2bf(f1.z), f2bf(f1.w)};
    *(short8*)(out + c * 8) = *(const short8*)o;
}

// hi = bf16(x), lo = bf16(x - f32(hi))  (split precision for the recurrence)
__global__ __launch_bounds__(256) void cvt_split(const float* __restrict__ in,
                                                 ushort_t* __restrict__ hi,
                                                 ushort_t* __restrict__ lo, long n8) {
    long c = (long)blockIdx.x * blockDim.x + threadIdx.x;
    if (c >= n8) return;
    const float* s = in + c * 8;
    ushort_t oh[8], ol[8];
    #pragma unroll
    for (int j = 0; j < 8; ++j) {
        float x = s[j];
        unsigned short h = f2bf(x);
        oh[j] = h;
        ol[j] = f2bf(x - bf2f(h));
    }
    *(short8*)(hi + c * 8) = *(const short8*)oh;
    *(short8*)(lo + c * 8) = *(const short8*)ol;
}

// A_g[r][k] = bf16(emb[idx[b*T + t]][k]),  r = t*16 + b
__global__ __launch_bounds__(256) void gather_cvt(const int* __restrict__ idx,
                                                  const float* __restrict__ emb,
                                                  ushort_t* __restrict__ Ag) {
    int c = blockIdx.x * blockDim.x + threadIdx.x;      // 2048*128 chunks of 8
    int r = c >> 7, kc = (c & 127) * 8;
    int t = r >> 4, b = r & 15;
    const float* s = emb + (size_t)idx[b * TSTEPS + t] * DIMS + kc;
    float4 f0 = *(const float4*)(s);
    float4 f1 = *(const float4*)(s + 4);
    ushort_t o[8] = {f2bf(f0.x), f2bf(f0.y), f2bf(f0.z), f2bf(f0.w),
                     f2bf(f1.x), f2bf(f1.y), f2bf(f1.z), f2bf(f1.w)};
    *(short8*)(Ag + (size_t)r * DIMS + kc) = *(const short8*)o;
}

// zero h0 (both planes) and c state; 64 blocks x 256 = 16384 threads
__global__ void zero_init(ushort_t* __restrict__ h_hi, ushort_t* __restrict__ h_lo,
                          float* __restrict__ c) {
    int i = blockIdx.x * blockDim.x + threadIdx.x;
    h_hi[i] = 0; h_lo[i] = 0; c[i] = 0.f;
}

// ---------------------------------------------------------------------------
// bf16 MFMA GEMM: C[M,N] = A[M,K](bf16) @ B[N,K]^T + bias, f32 out.
// 128x128 tile, BK=32, 256 thr (4 waves, 2x2), 16x16x32 MFMA, 4x4 frags/wave.
// LDS chunks XOR-swizzled: slot (row, cc) holds source chunk cc ^ ((row>>1)&3)
// -> frag ds_read_b128 spreads 16 lanes over 8 bank-groups (2-way = free).
// BSRC_F32: stage B by reg-converting f32 -> bf16 (fallback when ws is small).
// ---------------------------------------------------------------------------
template <int BSRC_F32>
__global__ __launch_bounds__(256, 2)
void gemm_bf16(const ushort_t* __restrict__ A,
               const void* __restrict__ Bv,
               const float* __restrict__ bias,
               float* __restrict__ C,
               int N, int K)
{
    __shared__ ushort_t As[2][128 * 32];
    __shared__ ushort_t Bs[2][128 * 32];

    const int tid  = threadIdx.x;
    const int lane = tid & 63;
    const int wid  = tid >> 6;
    const int m0   = blockIdx.y * 128;
    const int n0   = blockIdx.x * 128;

    // ---- staging addresses (2 x 16B chunks per thread per matrix) ----
    const int q  = tid >> 2;                       // tile row (inst0); inst1 = 64+q
    const int sc = ((tid & 3) ^ ((tid >> 3) & 3)) * 8;   // swizzled elem offset
    const ushort_t* gA0 = A + (size_t)(m0 + q) * K + sc;
    const ushort_t* gA1 = A + (size_t)(m0 + 64 + q) * K + sc;
    const ushort_t* gB0_bf = nullptr; const ushort_t* gB1_bf = nullptr;
    const float*    gB0_f  = nullptr; const float*    gB1_f  = nullptr;
    if (BSRC_F32) {
        gB0_f = (const float*)Bv + (size_t)(n0 + q) * K + sc;
        gB1_f = (const float*)Bv + (size_t)(n0 + 64 + q) * K + sc;
    } else {
        gB0_bf = (const ushort_t*)Bv + (size_t)(n0 + q) * K + sc;
        gB1_bf = (const ushort_t*)Bv + (size_t)(n0 + 64 + q) * K + sc;
    }
    char* AldsB = (char*)&As[0][0] + wid * 1024;   // wave-uniform base
    char* BldsB = (char*)&Bs[0][0] + wid * 1024;
    const int ldsTid = tid * 16;                   // linear slot for reg-staged B

    // ---- fragment read addresses (lane-constant swizzle) ----
    const int swz = ((lane >> 4) ^ ((lane >> 1) & 3)) * 16;   // byte pos of chunk
    const int wm = wid >> 1, wn = wid & 1;
    // byte offset of A frag mi: (wm*64 + mi*16 + (lane&15))*64 + swz
    const int aBase = (wm * 64 + (lane & 15)) * 64 + swz;
    const int bBase = (wn * 64 + (lane & 15)) * 64 + swz;

    f32x4 acc[4][4];
    #pragma unroll
    for (int i = 0; i < 4; ++i)
        #pragma unroll
        for (int j = 0; j < 4; ++j) acc[i][j] = (f32x4){0.f, 0.f, 0.f, 0.f};

    const int NT = K / 32;

    // stage tile 0 into buf 0
    {
        gload_lds16(gA0, AldsB);
        gload_lds16(gA1, AldsB + 4096);
        if (BSRC_F32) {
            float4 f0 = *(const float4*)(gB0_f);
            float4 f1 = *(const float4*)(gB0_f + 4);
            float4 f2 = *(const float4*)(gB1_f);
            float4 f3 = *(const float4*)(gB1_f + 4);
            ushort_t p0[8] = {f2bf(f0.x), f2bf(f0.y), f2bf(f0.z), f2bf(f0.w),
                              f2bf(f1.x), f2bf(f1.y), f2bf(f1.z), f2bf(f1.w)};
            ushort_t p1[8] = {f2bf(f2.x), f2bf(f2.y), f2bf(f2.z), f2bf(f2.w),
                              f2bf(f3.x), f2bf(f3.y), f2bf(f3.z), f2bf(f3.w)};
            *(short8*)((char*)&Bs[0][0] + ldsTid)        = *(const short8*)p0;
            *(short8*)((char*)&Bs[0][0] + 4096 + ldsTid) = *(const short8*)p1;
        } else {
            gload_lds16(gB0_bf, BldsB);
            gload_lds16(gB1_bf, BldsB + 4096);
        }
    }
    __syncthreads();

    for (int t = 0; t < NT; ++t) {
        const int cur = t & 1;
        // stage next tile into other buffer (loads fly during this compute)
        if (t + 1 < NT) {
            const int koff = (t + 1) * 32;
            const int nxt  = cur ^ 1;
            gload_lds16(gA0 + koff, (char*)&As[nxt][0] + wid * 1024);
            gload_lds16(gA1 + koff, (char*)&As[nxt][0] + wid * 1024 + 4096);
            if (BSRC_F32) {
                float4 f0 = *(const float4*)(gB0_f + koff);
                float4 f1 = *(const float4*)(gB0_f + koff + 4);
                float4 f2 = *(const float4*)(gB1_f + koff);
                float4 f3 = *(const float4*)(gB1_f + koff + 4);
                ushort_t p0[8] = {f2bf(f0.x), f2bf(f0.y), f2bf(f0.z), f2bf(f0.w),
                                  f2bf(f1.x), f2bf(f1.y), f2bf(f1.z), f2bf(f1.w)};
                ushort_t p1[8] = {f2bf(f2.x), f2bf(f2.y), f2bf(f2.z), f2bf(f2.w),
                                  f2bf(f3.x), f2bf(f3.y), f2bf(f3.z), f2bf(f3.w)};
                *(short8*)((char*)&Bs[nxt][0] + ldsTid)        = *(const short8*)p0;
                *(short8*)((char*)&Bs[nxt][0] + 4096 + ldsTid) = *(const short8*)p1;
            } else {
                gload_lds16(gB0_bf + koff, (char*)&Bs[nxt][0] + wid * 1024);
                gload_lds16(gB1_bf + koff, (char*)&Bs[nxt][0] + wid * 1024 + 4096);
            }
        }
        // compute current tile
        const char* Ab = (const char*)&As[cur][0];
        const char* Bb = (const char*)&Bs[cur][0];
        short8 af[4], bf[4];
        #pragma unroll
        for (int i = 0; i < 4; ++i) af[i] = *(const short8*)(Ab + aBase + i * 1024);
        #pragma unroll
        for (int j = 0; j < 4; ++j) bf[j] = *(const short8*)(Bb + bBase + j * 1024);
        #pragma unroll
        for (int i = 0; i < 4; ++i)
            #pragma unroll
            for (int j = 0; j < 4; ++j)
                acc[i][j] = __builtin_amdgcn_mfma_f32_16x16x32_bf16(
                    af[i], bf[j], acc[i][j], 0, 0, 0);
        __syncthreads();
    }

    // epilogue: D col = lane&15, row = (lane>>4)*4 + r
    #pragma unroll
    for (int j = 0; j < 4; ++j) {
        const int col = n0 + wn * 64 + j * 16 + (lane & 15);
        const float bv = bias[col];
        #pragma unroll
        for (int i = 0; i < 4; ++i) {
            const int row = m0 + wm * 64 + i * 16 + (lane >> 4) * 4;
            #pragma unroll
            for (int r = 0; r < 4; ++r)
                C[(size_t)(row + r) * N + col] = acc[i][j][r] + bv;
        }
    }
}

// ---------------------------------------------------------------------------
// One LSTM step via MFMA, split-bf16 (Whi*hhi + Whi*hlo + Wlo*hhi ~ f32).
// 64 blocks x 512 thr (8 waves). wave w: gate = w&3, K-half = w>>2.
// Block owns d0..d0+15; gates exchanged via LDS; c state f32 in global.
// ---------------------------------------------------------------------------
__global__ __launch_bounds__(512, 2)
void lstm_step_mfma(const float* __restrict__ gx,       // [2048][4096]
                    const ushort_t* __restrict__ WhHi,  // [4096][1024]
                    const ushort_t* __restrict__ WhLo,
                    ushort_t* __restrict__ hHi,         // [129][16][1024]
                    ushort_t* __restrict__ hLo,
                    float* __restrict__ cSt,            // [16][1024]
                    int t)
{
    __shared__ float g_xch[8][256];

    const int tid  = threadIdx.x;
    const int l    = tid & 63;
    const int w    = tid >> 6;
    const int gate = w & 3;
    const int kh   = w >> 2;             // K-half: 0 -> k 0..511, 1 -> 512..1023
    const int d0   = blockIdx.x * 16;
    const int b    = l & 15;

    const int jrow  = gate * DIMS + d0 + (l & 15);        // A row (Wh)
    const int kbase = kh * 512 + (l >> 4) * 8;

    const ushort_t* pAh = WhHi + (size_t)jrow * DIMS + kbase;
    const ushort_t* pAl = WhLo + (size_t)jrow * DIMS + kbase;
    const ushort_t* pBh = hHi + (size_t)t * (BATCH * DIMS) + b * DIMS + kbase;
    const ushort_t* pBl = hLo + (size_t)t * (BATCH * DIMS) + b * DIMS + kbase;

    f32x4 aHH = (f32x4){0.f, 0.f, 0.f, 0.f};
    f32x4 aHL = aHH, aLH = aHH;
    #pragma unroll 8
    for (int kb = 0; kb < 16; ++kb) {
        short8 ah = *(const short8*)(pAh + kb * 32);
        short8 al = *(const short8*)(pAl + kb * 32);
        short8 bh = *(const short8*)(pBh + kb * 32);
        short8 bl = *(const short8*)(pBl + kb * 32);
        aHH = __builtin_amdgcn_mfma_f32_16x16x32_bf16(ah, bh, aHH, 0, 0, 0);
        aHL = __builtin_amdgcn_mfma_f32_16x16x32_bf16(ah, bl, aHL, 0, 0, 0);
        aLH = __builtin_amdgcn_mfma_f32_16x16x32_bf16(al, bh, aLH, 0, 0, 0);
    }
    f32x4 acc = aHH + aHL + aLH;

    // add gx (only K-half 0 waves, once): lane l covers j = jl0..jl0+3, b
    if (kh == 0) {
        const float4 gxv = *(const float4*)(gx + ((size_t)t * 16 + b) * GDIM
                                            + gate * DIMS + d0 + (l >> 4) * 4);
        acc[0] += gxv.x; acc[1] += gxv.y; acc[2] += gxv.z; acc[3] += gxv.w;
    }
    // D row = (l>>4)*4 + r (local j), col = b
    #pragma unroll
    for (int r = 0; r < 4; ++r)
        g_xch[w][((l >> 4) * 4 + r) * 16 + b] = acc[r];
    __syncthreads();

    if (w == 0) {   // cell update: lane l handles b, d-locals dg*4+q
        const int dg = l >> 4;
        float* cp = cSt + b * DIMS + d0 + dg * 4;
        ushort_t o_hi[4], o_lo[4];
        #pragma unroll
        for (int q = 0; q < 4; ++q) {
            const int o = (dg * 4 + q) * 16 + b;
            float iv = sigmoidf_(g_xch[0][o] + g_xch[4][o]);
            float fv = sigmoidf_(g_xch[1][o] + g_xch[5][o]);
            float ov = sigmoidf_(g_xch[2][o] + g_xch[6][o]);
            float gv = tanhf    (g_xch[3][o] + g_xch[7][o]);
            float cn = fv * cp[q] + iv * gv;
            cp[q] = cn;
            float hn = ov * tanhf(cn);
            unsigned short hi = f2bf(hn);
            o_hi[q] = hi;
            o_lo[q] = f2bf(hn - bf2f(hi));
        }
        size_t ho = (size_t)(t + 1) * (BATCH * DIMS) + b * DIMS + d0 + dg * 4;
        *(ushort4*)(hHi + ho) = *(const ushort4*)o_hi;
        *(ushort4*)(hLo + ho) = *(const ushort4*)o_lo;
    }
}

// ---------------------------------------------------------------------------
// In-place log-softmax over each row of out[2048][32000] (unchanged).
// ---------------------------------------------------------------------------
__device__ __forceinline__ float wave_max_(float v) {
    #pragma unroll
    for (int off = 32; off > 0; off >>= 1) v = fmaxf(v, __shfl_xor(v, off));
    return v;
}
__device__ __forceinline__ float wave_sum_(float v) {
    #pragma unroll
    for (int off = 32; off > 0; off >>= 1) v += __shfl_xor(v, off);
    return v;
}

__global__ __launch_bounds__(256)
void logsoftmax_rows(float* __restrict__ out)
{
    float* rowp = out + (size_t)blockIdx.x * VOCAB;
    const int tid = threadIdx.x;
    __shared__ float redm[4], reds[4];

    float m = -INFINITY;
    for (int i = tid * 4; i < VOCAB; i += 1024) {
        float4 v = *(const float4*)(rowp + i);
        m = fmaxf(m, fmaxf(fmaxf(v.x, v.y), fmaxf(v.z, v.w)));
    }
    m = wave_max_(m);
    if ((tid & 63) == 0) redm[tid >> 6] = m;
    __syncthreads();
    m = fmaxf(fmaxf(redm[0], redm[1]), fmaxf(redm[2], redm[3]));

    float s = 0.f;
    for (int i = tid * 4; i < VOCAB; i += 1024) {
        float4 v = *(const float4*)(rowp + i);
        s += __expf(v.x - m) + __expf(v.y - m) + __expf(v.z - m) + __expf(v.w - m);
    }
    s = wave_sum_(s);
    if ((tid & 63) == 0) reds[tid >> 6] = s;
    __syncthreads();
    s = reds[0] + reds[1] + reds[2] + reds[3];
    const float lse = m + __logf(s);

    for (int i = tid * 4; i < VOCAB; i += 1024) {
        float4 v = *(const float4*)(rowp + i);
        v.x -= lse; v.y -= lse; v.z -= lse; v.w -= lse;
        *(float4*)(rowp + i) = v;
    }
}

// ---------------------------------------------------------------------------
// Orchestration
// ---------------------------------------------------------------------------
extern "C" void kernel_launch(void* const* d_in, const int* in_sizes, int n_in,
                              void* d_out, int out_size, void* d_ws, size_t ws_size,
                              hipStream_t stream)
{
    const int*   idx  = (const int*)  d_in[0];
    const float* emb  = (const float*)d_in[1];
    const float* Wx_w = (const float*)d_in[2];
    const float* Wx_b = (const float*)d_in[3];
    const float* Wh_w = (const float*)d_in[4];
    const float* fc_w = (const float*)d_in[5];
    const float* fc_b = (const float*)d_in[6];
    float* out = (float*)d_out;

    // ws layout (256B aligned)
    char* base = (char*)d_ws;
    size_t off = 0;
    auto alloc = [&](size_t bytes) {
        size_t o = off; off = (off + bytes + 255) & ~(size_t)255; return o;
    };
    float*    gx   = (float*)   (base + alloc((size_t)2048 * GDIM * 4));
    ushort_t* Ag   = (ushort_t*)(base + alloc((size_t)2048 * DIMS * 2));
    ushort_t* WxB  = (ushort_t*)(base + alloc((size_t)GDIM * DIMS * 2));
    ushort_t* WhHi = (ushort_t*)(base + alloc((size_t)GDIM * DIMS * 2));
    ushort_t* WhLo = (ushort_t*)(base + alloc((size_t)GDIM * DIMS * 2));
    ushort_t* hHi  = (ushort_t*)(base + alloc((size_t)(TSTEPS + 1) * BATCH * DIMS * 2));
    ushort_t* hLo  = (ushort_t*)(base + alloc((size_t)(TSTEPS + 1) * BATCH * DIMS * 2));
    float*    cSt  = (float*)   (base + alloc((size_t)BATCH * DIMS * 4));
    size_t core_end = off;
    ushort_t* fcB  = (ushort_t*)(base + alloc((size_t)VOCAB * DIMS * 2));
    const bool haveFcB = (off <= ws_size);
    (void)core_end;

    // --- conversions ---
    cvt_bf16 <<<(GDIM * DIMS / 8) / 256, 256, 0, stream>>>(Wx_w, WxB, GDIM * DIMS / 8);
    cvt_split<<<(GDIM * DIMS / 8) / 256, 256, 0, stream>>>(Wh_w, WhHi, WhLo, GDIM * DIMS / 8);
    if (haveFcB)
        cvt_bf16<<<((size_t)VOCAB * DIMS / 8) / 256, 256, 0, stream>>>(
            fc_w, fcB, (long)VOCAB * DIMS / 8);
    gather_cvt<<<(2048 * 128) / 256, 256, 0, stream>>>(idx, emb, Ag);
    zero_init<<<64, 256, 0, stream>>>(hHi, hLo, cSt);

    // --- GEMM1: gx = Ag @ WxB^T + Wx_b  [2048 x 4096] ---
    {
        dim3 grid(GDIM / 128, 2048 / 128);
        gemm_bf16<0><<<grid, 256, 0, stream>>>(Ag, (const void*)WxB, Wx_b, gx,
                                               GDIM, DIMS);
    }

    // --- recurrence: 128 MFMA step kernels ---
    for (int t = 0; t < TSTEPS; ++t)
        lstm_step_mfma<<<64, 512, 0, stream>>>(gx, WhHi, WhLo, hHi, hLo, cSt, t);

    // --- GEMM2: out = H(bf16) @ fc^T + fc_b  [2048 x 32000] ---
    {
        dim3 grid(VOCAB / 128, 2048 / 128);
        const ushort_t* Hrows = hHi + (size_t)BATCH * DIMS;   // slots 1..128
        if (haveFcB)
            gemm_bf16<0><<<grid, 256, 0, stream>>>(Hrows, (const void*)fcB, fc_b,
                                                   out, VOCAB, DIMS);
        else
            gemm_bf16<1><<<grid, 256, 0, stream>>>(Hrows, (const void*)fc_w, fc_b,
                                                   out, VOCAB, DIMS);
    }

    // --- log-softmax ---
    logsoftmax_rows<<<TSTEPS * BATCH, 256, 0, stream>>>(out);
}